// Round 8
// baseline (878.832 us; speedup 1.0000x reference)
//
#include <hip/hip_runtime.h>
#include <math.h>

constexpr int CIN   = 96;
constexpr int COUT  = 192;
constexpr int NSC   = 1 << 19;   // key space 8*40*40*40 = 512000 <= NSC
constexpr int LDW   = 104;       // LDS row stride (shorts): 2-way-free for b128

typedef short v8s  __attribute__((ext_vector_type(8)));
typedef float f32x4 __attribute__((ext_vector_type(4)));

__device__ __forceinline__ unsigned short f2bf(float f) {
  unsigned u = __float_as_uint(f);
  u += 0x7fff + ((u >> 16) & 1);          // RNE
  return (unsigned short)(u >> 16);
}
__device__ __forceinline__ float bf2f(unsigned short s) {
  return __uint_as_float((unsigned)s << 16);
}
// fields: [62:42] presence sum (rank), [20:0] count sum (pos). No carry: both < 2^21.
__device__ __forceinline__ unsigned long long pack2(int c) {
  return ((unsigned long long)(c > 0) << 42) | (unsigned)c;
}

// ---------------- zero cntk + convert W -> bf16 ----------------
__global__ void k_zero(int4* __restrict__ cntk4, int n4,
                       const float4* __restrict__ W4, unsigned short* __restrict__ Wbf) {
  int i = blockIdx.x * blockDim.x + threadIdx.x;
  int s = gridDim.x * blockDim.x;
  int4 z = make_int4(0, 0, 0, 0);
  for (int j = i; j < n4; j += s) cntk4[j] = z;
  for (int j = i; j < (COUT * CIN / 4); j += s) {
    float4 w = W4[j];
    uint2 pk;
    pk.x = (unsigned)f2bf(w.x) | ((unsigned)f2bf(w.y) << 16);
    pk.y = (unsigned)f2bf(w.z) | ((unsigned)f2bf(w.w) << 16);
    ((uint2*)Wbf)[j] = pk;
  }
}

// ---------------- keys + per-point slot + per-key counts ----------------
__global__ void k_key(const float* __restrict__ xyz, const int* __restrict__ batch,
                      int* __restrict__ keys, int* __restrict__ slot,
                      int* __restrict__ cntk, int n) {
  int i = blockIdx.x * blockDim.x + threadIdx.x;
  if (i >= n) return;
  int vx = min(max((int)floorf(xyz[3*i+0] * 0.5f), 0), 39);
  int vy = min(max((int)floorf(xyz[3*i+1] * 0.5f), 0), 39);
  int vz = min(max((int)floorf(xyz[3*i+2] * 0.5f), 0), 39);
  int key = ((batch[i] * 40 + vx) * 40 + vy) * 40 + vz;   // lexicographic, < 512000
  keys[i] = key;
  slot[i] = atomicAdd(&cntk[key], 1);
}

// ---------------- dual prefix scan over key counts ----------------
__global__ void k_scan1(const int4* __restrict__ cnt4,
                        unsigned long long* __restrict__ bsums) {
  int t = threadIdx.x;
  int4 v = cnt4[(size_t)blockIdx.x * 256 + t];
  unsigned long long s = pack2(v.x) + pack2(v.y) + pack2(v.z) + pack2(v.w);
  for (int o = 32; o; o >>= 1) s += __shfl_down(s, o);
  __shared__ unsigned long long wsum[4];
  if ((t & 63) == 0) wsum[t >> 6] = s;
  __syncthreads();
  if (t == 0) bsums[blockIdx.x] = wsum[0] + wsum[1] + wsum[2] + wsum[3];
}

__global__ void k_scan2(const unsigned long long* __restrict__ bsums,
                        unsigned long long* __restrict__ boffs,
                        int* __restrict__ hdr) {
  __shared__ unsigned long long tmp[256];
  int t = threadIdx.x;                      // 256 threads, 512 sums
  unsigned long long v0 = bsums[2*t], v1 = bsums[2*t+1];
  unsigned long long s = v0 + v1;
  tmp[t] = s;
  __syncthreads();
  for (int o = 1; o < 256; o <<= 1) {
    unsigned long long x = (t >= o) ? tmp[t - o] : 0ULL;
    __syncthreads();
    tmp[t] += x;
    __syncthreads();
  }
  unsigned long long base = tmp[t] - s;
  boffs[2*t] = base;
  boffs[2*t+1] = base + v0;
  if (t == 255) hdr[0] = (int)(tmp[255] >> 42);   // num_unique
}

// meta[key] = rank<<40 | pos<<16 | min(cnt,65535)
__global__ void k_scan3(const int4* __restrict__ cnt4,
                        const unsigned long long* __restrict__ boffs,
                        unsigned long long* __restrict__ meta) {
  int t = threadIdx.x, b = blockIdx.x;
  int4 v = cnt4[(size_t)b * 256 + t];
  unsigned long long q0 = pack2(v.x), q1 = pack2(v.y), q2 = pack2(v.z), q3 = pack2(v.w);
  unsigned long long s = q0 + q1 + q2 + q3;
  __shared__ unsigned long long tmp[256];
  tmp[t] = s;
  __syncthreads();
  for (int o = 1; o < 256; o <<= 1) {
    unsigned long long x = (t >= o) ? tmp[t - o] : 0ULL;
    __syncthreads();
    tmp[t] += x;
    __syncthreads();
  }
  unsigned long long e0 = boffs[b] + tmp[t] - s;
  unsigned long long e1 = e0 + q0, e2 = e1 + q1, e3 = e2 + q2;
  size_t idx = ((size_t)b * 256 + t) * 4;
  const unsigned long long M = 0x1FFFFF;
  meta[idx+0] = ((e0>>42)<<40) | ((e0 & M)<<16) | (unsigned long long)min(v.x, 65535);
  meta[idx+1] = ((e1>>42)<<40) | ((e1 & M)<<16) | (unsigned long long)min(v.y, 65535);
  meta[idx+2] = ((e2>>42)<<40) | ((e2 & M)<<16) | (unsigned long long)min(v.z, 65535);
  meta[idx+3] = ((e3>>42)<<40) | ((e3 & M)<<16) | (unsigned long long)min(v.w, 65535);
}

// ---------------- permuted 32B record stream ----------------
// rec[p] (8 words): xyz.xyz, xyzc, pidx|batch<<20, segbase|cnt<<20, rank, pad
__global__ void k_plist(const float* __restrict__ xyz, const float* __restrict__ xyzc,
                        const int* __restrict__ batch, const int* __restrict__ keys,
                        const int* __restrict__ slot,
                        const unsigned long long* __restrict__ meta,
                        uint4* __restrict__ rec, long long n) {
  long long i = (long long)blockIdx.x * blockDim.x + threadIdx.x;
  if (i >= n) return;
  unsigned long long m = meta[keys[i]];
  unsigned rank = (unsigned)(m >> 40);
  unsigned pos  = (unsigned)((m >> 16) & 0xFFFFFF);
  unsigned cnt  = (unsigned)(m & 0xFFFF);
  unsigned p = pos + (unsigned)slot[i];
  uint4 a, b;
  a.x = __float_as_uint(xyz[3*i+0]);
  a.y = __float_as_uint(xyz[3*i+1]);
  a.z = __float_as_uint(xyz[3*i+2]);
  a.w = __float_as_uint(xyzc[i]);
  b.x = (unsigned)i | ((unsigned)batch[i] << 20);
  b.y = pos | (cnt << 20);
  b.z = rank;
  b.w = 0;
  rec[(size_t)p*2+0] = a;
  rec[(size_t)p*2+1] = b;
}

// ---------------- fused LN + MFMA + segment-max + scalars (wave windows) ----------------
__device__ __forceinline__ void ln_to_lds(const float* __restrict__ feat,
                                          const int (*__restrict__ T)[8], int pt, int RL,
                                          int lane, unsigned short* __restrict__ HlW,
                                          const float* __restrict__ g_lds,
                                          const float* __restrict__ b_lds) {
  int q = lane & 3;
  if (pt < RL) {
    int pidx = T[pt][4] & 0xFFFFF;
    const float* fr = feat + (size_t)pidx * CIN + q * 24;
    float fv[24]; float sum = 0.f, sq = 0.f;
    #pragma unroll
    for (int j = 0; j < 24; j += 4) {
      float4 x = *(const float4*)(fr + j);
      fv[j] = x.x; fv[j+1] = x.y; fv[j+2] = x.z; fv[j+3] = x.w;
    }
    #pragma unroll
    for (int j = 0; j < 24; j++) { sum += fv[j]; sq += fv[j] * fv[j]; }
    sum += __shfl_xor(sum, 1); sq += __shfl_xor(sq, 1);
    sum += __shfl_xor(sum, 2); sq += __shfl_xor(sq, 2);
    float mu   = sum * (1.f / CIN);
    float var  = sq  * (1.f / CIN) - mu * mu;
    float rstd = rsqrtf(var + 1e-6f);
    unsigned pk[12];
    #pragma unroll
    for (int j = 0; j < 12; j++) {
      int k = q * 24 + 2 * j;
      float v0 = (fv[2*j]   - mu) * rstd * g_lds[k]   + b_lds[k];
      float v1 = (fv[2*j+1] - mu) * rstd * g_lds[k+1] + b_lds[k+1];
      pk[j] = (unsigned)f2bf(v0) | ((unsigned)f2bf(v1) << 16);
    }
    uint4* dst = (uint4*)&HlW[(lane >> 2) * LDW + q * 24];
    dst[0] = make_uint4(pk[0], pk[1], pk[2],  pk[3]);
    dst[1] = make_uint4(pk[4], pk[5], pk[6],  pk[7]);
    dst[2] = make_uint4(pk[8], pk[9], pk[10], pk[11]);
  }
}

__device__ __forceinline__ void mfma12(const unsigned short* __restrict__ HlW,
                                       const unsigned short* __restrict__ Wl,
                                       int lane, f32x4 (&acc)[12]) {
  int r = lane & 15, koff = (lane >> 4) * 8;
  #pragma unroll
  for (int ks = 0; ks < 3; ks++) {
    v8s a = *(const v8s*)&HlW[r * LDW + ks * 32 + koff];
    #pragma unroll
    for (int t16 = 0; t16 < 12; t16++) {
      v8s b = *(const v8s*)&Wl[(t16 * 16 + r) * LDW + ks * 32 + koff];
      acc[t16] = __builtin_amdgcn_mfma_f32_16x16x32_bf16(a, b, acc[t16], 0, 0, 0);
    }
  }
}

__global__ __launch_bounds__(256) void k_F(
    const float* __restrict__ feat, const unsigned short* __restrict__ Wbf,
    const float* __restrict__ gamma, const float* __restrict__ beta,
    const uint4* __restrict__ rec, const int* __restrict__ hdr,
    float* __restrict__ out, long long n, int nbF) {
  int t = threadIdx.x;
  int lane = t & 63, wv = t >> 6;
  float* ocrd = out + n * 192;
  float* oxyz = out + n * 196;
  float* ocnt = out + n * 199;
  float* obat = out + n * 200;
  float* oval = out + n * 201;

  if ((int)blockIdx.x >= nbF) {               // ---- tail role (rows >= num_unique) ----
    int nu = hdr[0];
    long long s = (long long)((int)blockIdx.x - nbF) * 4 + wv;
    if (s < nu || s >= n) return;
    float* orow = out + s * COUT;
    orow[lane] = 0.f; orow[lane + 64] = 0.f; orow[lane + 128] = 0.f;
    if (lane == 0) {
      oxyz[s*3+0] = 0.f; oxyz[s*3+1] = 0.f; oxyz[s*3+2] = 0.f;
      ocnt[s] = 1.0f;  obat[s] = 0.f;  oval[s] = 0.f;
      ocrd[s*4+0] = 0.f; ocrd[s*4+1] = 0.f; ocrd[s*4+2] = 0.f; ocrd[s*4+3] = 0.f;
    }
    return;
  }

  __shared__ unsigned short Wl[COUT * LDW];   // 39936 B
  __shared__ unsigned short Hl[4][16 * LDW];  // 13312 B (per-wave 16-row A tiles)
  __shared__ int Tl[4][32][8];                // 4096 B staged records
  __shared__ float g_lds[CIN], b_lds[CIN];
  if (t < CIN) { g_lds[t] = gamma[t]; b_lds[t] = beta[t]; }
  #pragma unroll
  for (int i = 0; i < 9; i++) {               // stage W (bf16): 2304 uint4
    int j = t + 256 * i;
    uint4 w = ((const uint4*)Wbf)[j];
    int flat = j * 8, row = flat / CIN, col = flat % CIN;
    *(uint4*)&Wl[row * LDW + col] = w;
  }
  __syncthreads();                            // only block-wide barrier

  int gw = (int)blockIdx.x * 4 + wv;
  long long p0l = (long long)gw * 16;
  if (p0l >= n) return;                       // whole wave exits (after barrier)
  int p0 = (int)p0l;

  // ---- wave window ownership: [first head >= p0, first head >= p0+16) ----
  uint4 rb0 = rec[(size_t)p0 * 2 + 1];
  int base0 = rb0.y & 0xFFFFF, cnt0 = (int)(rb0.y >> 20);
  int rs = (base0 == p0) ? p0 : base0 + cnt0;
  int p1 = p0 + 16;
  int re;
  if (p1 >= (int)n) re = (int)n;
  else {
    uint4 rb1 = rec[(size_t)p1 * 2 + 1];
    int b1 = rb1.y & 0xFFFFF, c1 = (int)(rb1.y >> 20);
    re = (b1 == p1) ? p1 : b1 + c1;
  }
  int RL = re - rs;                           // 0..~25 (<=32 by Poisson tail)

  if (lane < RL) {                            // stage records into Tl
    uint4 a = rec[(size_t)(rs + lane) * 2];
    uint4 b = rec[(size_t)(rs + lane) * 2 + 1];
    int* T = Tl[wv][lane];
    T[0]=(int)a.x; T[1]=(int)a.y; T[2]=(int)a.z; T[3]=(int)a.w;
    T[4]=(int)b.x; T[5]=(int)b.y; T[6]=(int)b.z; T[7]=(int)b.w;
  }
  __builtin_amdgcn_wave_barrier();
  asm volatile("s_waitcnt lgkmcnt(0)" ::: "memory");

  f32x4 acc0[12], acc1[12];
  #pragma unroll
  for (int i = 0; i < 12; i++) { acc0[i] = (f32x4){0.f,0.f,0.f,0.f}; acc1[i] = (f32x4){0.f,0.f,0.f,0.f}; }

  unsigned short* HlW = Hl[wv];
  ln_to_lds(feat, Tl[wv], (lane >> 2), RL, lane, HlW, g_lds, b_lds);
  __builtin_amdgcn_wave_barrier();
  asm volatile("s_waitcnt lgkmcnt(0)" ::: "memory");
  mfma12(HlW, Wl, lane, acc0);
  asm volatile("s_waitcnt lgkmcnt(0)" ::: "memory");
  if (RL > 16) {
    ln_to_lds(feat, Tl[wv], 16 + (lane >> 2), RL, lane, HlW, g_lds, b_lds);
    __builtin_amdgcn_wave_barrier();
    asm volatile("s_waitcnt lgkmcnt(0)" ::: "memory");
    mfma12(HlW, Wl, lane, acc1);
  }

  // ---- per-segment scalar sums + finalize (head lanes, divergent but tiny) ----
  bool head = false;
  if (lane < RL) head = ((Tl[wv][lane][5] & 0xFFFFF) == rs + lane);
  unsigned long long hm = __ballot(head);
  if (head) {
    int cnt  = (int)((unsigned)Tl[wv][lane][5] >> 20);
    int rank = Tl[wv][lane][6];
    float ax = 0.f, ay = 0.f, az = 0.f, ac = 0.f; int ab = 0;
    for (int qq = 0; qq < cnt; qq++) {
      const int* T2 = Tl[wv][lane + qq];
      float c = __int_as_float(T2[3]);
      ax += __int_as_float(T2[0]) * c;
      ay += __int_as_float(T2[1]) * c;
      az += __int_as_float(T2[2]) * c;
      ac += c;
      ab += (int)(((unsigned)T2[4] >> 20) & 0xFFF);
    }
    float cs = fmaxf(ac, 1.0f);
    float x = ax / cs, y = ay / cs, z = az / cs;
    int bn = ab / max(cnt, 1);
    oxyz[(size_t)rank*3+0] = x; oxyz[(size_t)rank*3+1] = y; oxyz[(size_t)rank*3+2] = z;
    ocnt[rank] = cs;
    obat[rank] = (float)bn;
    oval[rank] = 1.0f;
    ocrd[(size_t)rank*4+0] = (float)bn;
    ocrd[(size_t)rank*4+1] = (float)(int)floorf(x * 0.5f);
    ocrd[(size_t)rank*4+2] = (float)(int)floorf(y * 0.5f);
    ocrd[(size_t)rank*4+3] = (float)(int)floorf(z * 0.5f);
  }

  // ---- per-segment feat max from acc registers; write final f32 rows ----
  int rb = (lane >> 4) * 4;
  while (hm) {
    int j = __ffsll((unsigned long long)hm) - 1;
    hm &= hm - 1;
    int cnt  = (int)((unsigned)Tl[wv][j][5] >> 20);
    int rank = Tl[wv][j][6];
    int a = j, b = j + cnt;
    float* orow = out + (size_t)rank * COUT;
    #pragma unroll
    for (int t16 = 0; t16 < 12; t16++) {
      float m = -3.402823e38f;
      #pragma unroll
      for (int rr = 0; rr < 4; rr++) {
        int row = rb + rr;
        if (row >= a && row < b) m = fmaxf(m, acc0[t16][rr]);
      }
      if (RL > 16) {
        #pragma unroll
        for (int rr = 0; rr < 4; rr++) {
          int row = 16 + rb + rr;
          if (row >= a && row < b) m = fmaxf(m, acc1[t16][rr]);
        }
      }
      m = fmaxf(m, __shfl_xor(m, 16));
      m = fmaxf(m, __shfl_xor(m, 32));
      if (lane < 16) orow[t16 * 16 + lane] = m;
    }
  }
}

extern "C" void kernel_launch(void* const* d_in, const int* in_sizes, int n_in,
                              void* d_out, int out_size, void* d_ws, size_t ws_size,
                              hipStream_t stream) {
  const float* feat  = (const float*)d_in[0];
  const float* xyz   = (const float*)d_in[1];
  const float* xyzc  = (const float*)d_in[2];
  const int*   batch = (const int*)d_in[3];
  const float* W     = (const float*)d_in[4];
  const float* gamma = (const float*)d_in[5];
  const float* beta  = (const float*)d_in[6];
  long long n = in_sizes[3];
  float* out = (float*)d_out;

  // ---- workspace layout (~23 MB) ----
  char* wsb = (char*)d_ws;
  size_t off = 0;
  int* hdr   = (int*)wsb;              off += 256;                // hdr[0] = num_unique
  int* keys  = (int*)(wsb + off);      off += (size_t)n * 4;
  int* slot  = (int*)(wsb + off);      off += (size_t)n * 4;
  off = (off + 255) & ~(size_t)255;
  int* cntk  = (int*)(wsb + off);      off += (size_t)NSC * 4;    // zeroed by k_zero
  unsigned long long* meta  = (unsigned long long*)(wsb + off); off += (size_t)NSC * 8;
  unsigned long long* bsums = (unsigned long long*)(wsb + off); off += 512 * 8;
  unsigned long long* boffs = (unsigned long long*)(wsb + off); off += 512 * 8;
  unsigned short* Wbf = (unsigned short*)(wsb + off); off += (size_t)COUT * CIN * 2;
  off = (off + 255) & ~(size_t)255;
  uint4* rec = (uint4*)(wsb + off);    off += (size_t)n * 32;

  int nb   = (int)((n + 255) / 256);
  int nbF  = (int)((n + 63) / 64);     // gather blocks: 4 wave-windows of 16 each
  int ntail = (int)((n + 3) / 4);
  k_zero  <<<256, 256, 0, stream>>>((int4*)cntk, NSC / 4, (const float4*)W, Wbf);
  k_key   <<<nb, 256, 0, stream>>>(xyz, batch, keys, slot, cntk, (int)n);
  k_scan1 <<<NSC / 1024, 256, 0, stream>>>((const int4*)cntk, bsums);
  k_scan2 <<<1, 256, 0, stream>>>(bsums, boffs, hdr);
  k_scan3 <<<NSC / 1024, 256, 0, stream>>>((const int4*)cntk, boffs, meta);
  k_plist <<<nb, 256, 0, stream>>>(xyz, xyzc, batch, keys, slot, meta, rec, n);
  k_F     <<<nbF + ntail, 256, 0, stream>>>(feat, Wbf, gamma, beta, rec, hdr,
                                            out, n, nbF);
}

// Round 9
// 308.313 us; speedup vs baseline: 2.8505x; 2.8505x over previous
//
#include <hip/hip_runtime.h>
#include <math.h>

constexpr int CIN   = 96;
constexpr int COUT  = 192;
constexpr int NSC   = 1 << 19;   // scan span >= 8*40*40*40 = 512000 keys
constexpr int LDW   = 104;       // Hl/Wl row stride (shorts)
constexpr int OST   = 208;       // Ol staging row stride (shorts, 416B)
constexpr int TAILB = 48;        // tail record stride (bytes); 12 u32

typedef short v8s  __attribute__((ext_vector_type(8)));
typedef float f32x4 __attribute__((ext_vector_type(4)));

__device__ __forceinline__ unsigned short f2bf(float f) {
  unsigned u = __float_as_uint(f);
  u += 0x7fff + ((u >> 16) & 1);          // RNE
  return (unsigned short)(u >> 16);
}
__device__ __forceinline__ float bf2f(unsigned short s) {
  return __uint_as_float((unsigned)s << 16);
}
// fields: [62:42]=presence (rank), [41:21]=multi count (mpos), [20:0]=count (pos)
__device__ __forceinline__ unsigned long long pack3(int c) {
  return ((unsigned long long)(c > 0) << 42)
       | ((unsigned long long)((c >= 2) ? c : 0) << 21)
       | (unsigned long long)(unsigned)c;
}

// ---------------- zero cntk + convert W -> bf16 ----------------
__global__ void k_zero(int4* __restrict__ cntk4, int n4,
                       const float4* __restrict__ W4, unsigned short* __restrict__ Wbf) {
  int i = blockIdx.x * blockDim.x + threadIdx.x;
  int s = gridDim.x * blockDim.x;
  int4 z = make_int4(0, 0, 0, 0);
  for (int j = i; j < n4; j += s) cntk4[j] = z;
  for (int j = i; j < (COUT * CIN / 4); j += s) {   // 4608 float4
    float4 w = W4[j];
    uint2 pk;
    pk.x = (unsigned)f2bf(w.x) | ((unsigned)f2bf(w.y) << 16);
    pk.y = (unsigned)f2bf(w.z) | ((unsigned)f2bf(w.w) << 16);
    ((uint2*)Wbf)[j] = pk;
  }
}

// ---------------- keys + per-point slot + per-key counts ----------------
__global__ void k_key(const float* __restrict__ xyz, const int* __restrict__ batch,
                      int* __restrict__ keys, int* __restrict__ slot,
                      int* __restrict__ cntk, int n) {
  int i = blockIdx.x * blockDim.x + threadIdx.x;
  if (i >= n) return;
  int vx = min(max((int)floorf(xyz[3*i+0] * 0.5f), 0), 39);
  int vy = min(max((int)floorf(xyz[3*i+1] * 0.5f), 0), 39);
  int vz = min(max((int)floorf(xyz[3*i+2] * 0.5f), 0), 39);
  int key = ((batch[i] * 40 + vx) * 40 + vy) * 40 + vz;   // lexicographic, < 512000
  keys[i] = key;
  slot[i] = atomicAdd(&cntk[key], 1);
}

// ---------------- triple prefix scan ----------------
__global__ void k_scan1(const int4* __restrict__ cnt4,
                        unsigned long long* __restrict__ bsums) {
  int t = threadIdx.x;
  int4 v = cnt4[(size_t)blockIdx.x * 256 + t];
  unsigned long long s = pack3(v.x) + pack3(v.y) + pack3(v.z) + pack3(v.w);
  for (int o = 32; o; o >>= 1) s += __shfl_down(s, o);
  __shared__ unsigned long long wsum[4];
  if ((t & 63) == 0) wsum[t >> 6] = s;
  __syncthreads();
  if (t == 0) bsums[blockIdx.x] = wsum[0] + wsum[1] + wsum[2] + wsum[3];
}

__global__ void k_scan2(const unsigned long long* __restrict__ bsums,
                        unsigned long long* __restrict__ boffs,
                        int* __restrict__ hdr) {
  __shared__ unsigned long long tmp[256];
  int t = threadIdx.x;                      // 256 threads, 512 sums
  unsigned long long v0 = bsums[2*t], v1 = bsums[2*t+1];
  unsigned long long s = v0 + v1;
  tmp[t] = s;
  __syncthreads();
  for (int o = 1; o < 256; o <<= 1) {
    unsigned long long x = (t >= o) ? tmp[t - o] : 0ULL;
    __syncthreads();
    tmp[t] += x;
    __syncthreads();
  }
  unsigned long long base = tmp[t] - s;
  boffs[2*t] = base;
  boffs[2*t+1] = base + v0;
  if (t == 255) hdr[0] = (int)(tmp[255] >> 42);   // num_unique
}

__global__ void k_scan3(const int4* __restrict__ cnt4,
                        const unsigned long long* __restrict__ boffs,
                        int* __restrict__ rankK, int* __restrict__ posK,
                        int* __restrict__ mposK) {
  int t = threadIdx.x, b = blockIdx.x;
  int4 v = cnt4[(size_t)b * 256 + t];
  unsigned long long q0 = pack3(v.x), q1 = pack3(v.y), q2 = pack3(v.z), q3 = pack3(v.w);
  unsigned long long s = q0 + q1 + q2 + q3;
  __shared__ unsigned long long tmp[256];
  tmp[t] = s;
  __syncthreads();
  for (int o = 1; o < 256; o <<= 1) {
    unsigned long long x = (t >= o) ? tmp[t - o] : 0ULL;
    __syncthreads();
    tmp[t] += x;
    __syncthreads();
  }
  unsigned long long e0 = boffs[b] + tmp[t] - s;
  unsigned long long e1 = e0 + q0, e2 = e1 + q1, e3 = e2 + q2;
  const unsigned M = 0x1FFFFF;
  int4 rk = make_int4((int)(e0 >> 42), (int)(e1 >> 42), (int)(e2 >> 42), (int)(e3 >> 42));
  int4 mp = make_int4((int)((e0 >> 21) & M), (int)((e1 >> 21) & M),
                      (int)((e2 >> 21) & M), (int)((e3 >> 21) & M));
  int4 ps = make_int4((int)(e0 & M), (int)(e1 & M), (int)(e2 & M), (int)(e3 & M));
  ((int4*)rankK)[(size_t)b * 256 + t] = rk;
  ((int4*)posK )[(size_t)b * 256 + t] = ps;
  ((int4*)mposK)[(size_t)b * 256 + t] = mp;
}

// ---------------- LayerNorm + MFMA Linear -> direct out / overflow + tail ----------------
__global__ __launch_bounds__(256) void k_H(
    const float* __restrict__ feat, const float* __restrict__ xyz,
    const float* __restrict__ xyzc, const int* __restrict__ batch,
    const unsigned short* __restrict__ Wbf, const float* __restrict__ gamma,
    const float* __restrict__ beta, const int* __restrict__ keys,
    const int* __restrict__ slot, const int* __restrict__ cntk,
    const int* __restrict__ rankK, const int* __restrict__ posK,
    const int* __restrict__ mposK, float* __restrict__ out,
    unsigned short* __restrict__ ov, char* __restrict__ tail, long long n) {
  __shared__ unsigned short Wl[COUT * LDW];   // 39936B; reused as Ol[64][OST]
  __shared__ unsigned short Hl[64 * LDW];     // 13312B
  __shared__ float g_lds[CIN], b_lds[CIN];
  __shared__ int Tl[64][12];                  // scalar payload per point (48B recs)
  int t = threadIdx.x;
  if (t < CIN) { g_lds[t] = gamma[t]; b_lds[t] = beta[t]; }

  // ---- stage W (already bf16): 2304 uint4, 9 per thread ----
  #pragma unroll
  for (int i = 0; i < 9; i++) {
    int j = t + 256 * i;
    uint4 w = ((const uint4*)Wbf)[j];
    int flat = j * 8;
    int row = flat / CIN, col = flat % CIN;  // no row straddle (96 % 8 == 0)
    *(uint4*)&Wl[row * LDW + col] = w;
  }

  // ---- LayerNorm: 4 threads per point ----
  int p = t >> 2, q = t & 3;
  long long gp = (long long)blockIdx.x * 64 + p;
  if (q == 0 && gp < n) {                    // per-point scalar payload -> Tl
    int key = keys[gp];
    int sl  = slot[gp];
    Tl[p][0] = __float_as_int(xyz[gp*3+0]);
    Tl[p][1] = __float_as_int(xyz[gp*3+1]);
    Tl[p][2] = __float_as_int(xyz[gp*3+2]);
    Tl[p][3] = __float_as_int(xyzc[gp]);
    Tl[p][4] = batch[gp];
    Tl[p][5] = rankK[key];
    Tl[p][6] = posK[key];                    // segment base in point stream
    Tl[p][7] = cntk[key];
    Tl[p][8] = mposK[key];                   // segment base in overflow stream
    Tl[p][9] = sl;
    Tl[p][10] = 0; Tl[p][11] = 0;
  }
  float fv[24];
  float sum = 0.f, sq = 0.f;
  if (gp < n) {
    const float* fr = feat + gp * CIN + q * 24;
    #pragma unroll
    for (int j = 0; j < 24; j += 4) {
      float4 x = *(const float4*)(fr + j);
      fv[j] = x.x; fv[j+1] = x.y; fv[j+2] = x.z; fv[j+3] = x.w;
    }
    #pragma unroll
    for (int j = 0; j < 24; j++) { sum += fv[j]; sq += fv[j] * fv[j]; }
  } else {
    #pragma unroll
    for (int j = 0; j < 24; j++) fv[j] = 0.f;
  }
  sum += __shfl_xor(sum, 1); sq += __shfl_xor(sq, 1);
  sum += __shfl_xor(sum, 2); sq += __shfl_xor(sq, 2);
  float mu   = sum * (1.f / CIN);
  float var  = sq  * (1.f / CIN) - mu * mu;
  float rstd = rsqrtf(var + 1e-6f);
  __syncthreads();                            // g_lds/b_lds + Wl visible
  unsigned pk[12];
  #pragma unroll
  for (int j = 0; j < 12; j++) {
    int k = q * 24 + 2 * j;
    float v0 = (fv[2*j]   - mu) * rstd * g_lds[k]   + b_lds[k];
    float v1 = (fv[2*j+1] - mu) * rstd * g_lds[k+1] + b_lds[k+1];
    pk[j] = (unsigned)f2bf(v0) | ((unsigned)f2bf(v1) << 16);
  }
  {
    uint4* dst = (uint4*)&Hl[p * LDW + q * 24];
    dst[0] = make_uint4(pk[0], pk[1], pk[2],  pk[3]);
    dst[1] = make_uint4(pk[4], pk[5], pk[6],  pk[7]);
    dst[2] = make_uint4(pk[8], pk[9], pk[10], pk[11]);
  }
  __syncthreads();                            // Hl + Tl ready

  // ---- MFMA: 4 waves x 16 rows; N=192 (12 tiles), K=96 (3 steps) ----
  int wv = t >> 6, lane = t & 63, r = lane & 15, g = lane >> 4;
  f32x4 acc[12];
  #pragma unroll
  for (int i = 0; i < 12; i++) acc[i] = (f32x4){0.f, 0.f, 0.f, 0.f};
  int arow = (wv * 16 + r) * LDW;
  #pragma unroll
  for (int ks = 0; ks < 3; ks++) {
    v8s a = *(const v8s*)&Hl[arow + ks * 32 + g * 8];
    #pragma unroll
    for (int t16 = 0; t16 < 12; t16++) {
      v8s b = *(const v8s*)&Wl[(t16 * 16 + r) * LDW + ks * 32 + g * 8];
      acc[t16] = __builtin_amdgcn_mfma_f32_16x16x32_bf16(a, b, acc[t16], 0, 0, 0);
    }
  }
  __syncthreads();                            // Wl reads done -> reuse as Ol

  unsigned short* Ol = Wl;                    // [64][OST]
  #pragma unroll
  for (int t16 = 0; t16 < 12; t16++) {
    #pragma unroll
    for (int rr = 0; rr < 4; rr++) {
      Ol[(wv * 16 + g * 4 + rr) * OST + t16 * 16 + r] = f2bf(acc[t16][rr]);
    }
  }
  __syncthreads();

  // ---- store: 4 threads per point ----
  int row = t >> 2, c4 = t & 3;
  long long gp2 = (long long)blockIdx.x * 64 + row;
  if (gp2 < n) {
    int rk = Tl[row][5], cn = Tl[row][7], mb = Tl[row][8], sl = Tl[row][9];
    const unsigned short* src = &Ol[row * OST + c4 * 48];
    if (cn == 1) {                            // final output row, f32
      float* dst = out + (size_t)rk * COUT + c4 * 48;
      #pragma unroll
      for (int i = 0; i < 12; i++) {
        uint2 s2 = *(const uint2*)&src[i * 4];
        float4 f;
        f.x = bf2f((unsigned short)(s2.x & 0xffff));
        f.y = bf2f((unsigned short)(s2.x >> 16));
        f.z = bf2f((unsigned short)(s2.y & 0xffff));
        f.w = bf2f((unsigned short)(s2.y >> 16));
        *(float4*)&dst[i * 4] = f;
      }
    } else {                                  // overflow row, bf16
      unsigned short* dst = ov + (size_t)(mb + sl) * COUT + c4 * 48;
      #pragma unroll
      for (int i = 0; i < 6; i++)
        ((uint4*)dst)[i] = ((const uint4*)src)[i];
    }
    if (c4 == 0) {                            // 48B tail record at point-stream pos
      int pos = Tl[row][6] + sl;
      uint4* td = (uint4*)(tail + (size_t)pos * TAILB);
      const uint4* ts = (const uint4*)&Tl[row][0];
      td[0] = ts[0]; td[1] = ts[1]; td[2] = ts[2];
    }
  }
}

// ---------------- segment reduce (gather role) + tail defaults (tail role) ----------------
__global__ __launch_bounds__(256) void k_gat(
    const char* __restrict__ tail, const unsigned short* __restrict__ ov,
    const int* __restrict__ hdr, float* __restrict__ out, long long n, int nb64) {
  int t = threadIdx.x;
  int lane = t & 63, wv = t >> 6;
  float* ocrd = out + n * 192;
  float* oxyz = out + n * 196;
  float* ocnt = out + n * 199;
  float* obat = out + n * 200;
  float* oval = out + n * 201;

  if ((int)blockIdx.x >= nb64) {              // ---- tail role ----
    int nu = hdr[0];
    long long s = (long long)(blockIdx.x - nb64) * 4 + wv;
    if (s < nu || s >= n) return;
    float* orow = out + s * COUT;
    orow[lane] = 0.f; orow[lane + 64] = 0.f; orow[lane + 128] = 0.f;
    if (lane == 0) {
      oxyz[s*3+0] = 0.f; oxyz[s*3+1] = 0.f; oxyz[s*3+2] = 0.f;
      ocnt[s] = 1.0f;  obat[s] = 0.f;  oval[s] = 0.f;
      ocrd[s*4+0] = 0.f; ocrd[s*4+1] = 0.f; ocrd[s*4+2] = 0.f; ocrd[s*4+3] = 0.f;
    }
    return;
  }

  // ---- gather role: window of 64 point-stream records ----
  __shared__ int s_start[256], s_cnt[256], s_rank[256], s_mb[256];
  __shared__ int hscan[256];
  int p0 = blockIdx.x * 64;
  const int* t0 = (const int*)(tail + (size_t)p0 * TAILB);
  int base0 = t0[6], cnt0 = t0[7];
  int range_start = (base0 == p0) ? p0 : base0 + cnt0;
  int p1 = p0 + 64, range_end;
  if (p1 >= (int)n) {
    range_end = (int)n;
  } else {
    const int* t1 = (const int*)(tail + (size_t)p1 * TAILB);
    int base1 = t1[6], cnt1 = t1[7];
    range_end = (base1 == p1) ? p1 : base1 + cnt1;
  }
  int RL = range_end - range_start;
  int hd = 0, cn_ = 0, rk_ = 0, mb_ = 0;
  int pp = range_start + t;
  if (t < RL) {
    const int* tf = (const int*)(tail + (size_t)pp * TAILB);
    hd = (tf[6] == pp);
    if (hd) { cn_ = tf[7]; rk_ = tf[5]; mb_ = tf[8]; }
  }
  hscan[t] = hd;
  __syncthreads();
  for (int o = 1; o < 256; o <<= 1) {
    int x = (t >= o) ? hscan[t - o] : 0;
    __syncthreads();
    hscan[t] += x;
    __syncthreads();
  }
  int ns = hscan[255];
  if (hd) {
    int idx = hscan[t] - 1;
    s_start[idx] = pp; s_cnt[idx] = cn_; s_rank[idx] = rk_; s_mb[idx] = mb_;
  }
  __syncthreads();

  for (int j = wv; j < ns; j += 4) {
    int st = s_start[j], cn = s_cnt[j], rk = s_rank[j], mb = s_mb[j];
    // scalar sums over the segment's tail records
    float ax = 0.f, ay = 0.f, az = 0.f, ac = 0.f; int ab = 0;
    for (int qq = lane; qq < cn; qq += 64) {
      const float* tf = (const float*)(tail + (size_t)(st + qq) * TAILB);
      float c = tf[3];
      ax += tf[0] * c; ay += tf[1] * c; az += tf[2] * c; ac += c;
      ab += ((const int*)tf)[4];
    }
    for (int o = 32; o; o >>= 1) {
      ax += __shfl_down(ax, o); ay += __shfl_down(ay, o);
      az += __shfl_down(az, o); ac += __shfl_down(ac, o);
      ab += __shfl_down(ab, o);
    }
    if (cn > 1) {                             // feat max from overflow stream
      float ni = __int_as_float(0xff800000);
      float m0 = ni, m1 = ni, m2 = ni;
      for (int qq = 0; qq < cn; qq++) {
        const unsigned short* h = ov + (size_t)(mb + qq) * COUT;
        m0 = fmaxf(m0, bf2f(h[lane]));
        m1 = fmaxf(m1, bf2f(h[lane + 64]));
        m2 = fmaxf(m2, bf2f(h[lane + 128]));
      }
      float* orow = out + (size_t)rk * COUT;
      orow[lane] = m0; orow[lane + 64] = m1; orow[lane + 128] = m2;
    }
    if (lane == 0) {
      float cs = fmaxf(ac, 1.0f);
      float x = ax / cs, y = ay / cs, z = az / cs;
      int bn = ab / max(cn, 1);
      oxyz[rk*3+0] = x; oxyz[rk*3+1] = y; oxyz[rk*3+2] = z;
      ocnt[rk] = cs;
      obat[rk] = (float)bn;
      oval[rk] = 1.0f;
      ocrd[rk*4+0] = (float)bn;
      ocrd[rk*4+1] = (float)(int)floorf(x * 0.5f);
      ocrd[rk*4+2] = (float)(int)floorf(y * 0.5f);
      ocrd[rk*4+3] = (float)(int)floorf(z * 0.5f);
    }
  }
}

extern "C" void kernel_launch(void* const* d_in, const int* in_sizes, int n_in,
                              void* d_out, int out_size, void* d_ws, size_t ws_size,
                              hipStream_t stream) {
  const float* feat  = (const float*)d_in[0];
  const float* xyz   = (const float*)d_in[1];
  const float* xyzc  = (const float*)d_in[2];
  const int*   batch = (const int*)d_in[3];
  const float* W     = (const float*)d_in[4];
  const float* gamma = (const float*)d_in[5];
  const float* beta  = (const float*)d_in[6];
  long long n = in_sizes[3];
  float* out = (float*)d_out;

  // ---- workspace layout (~200 MB) ----
  char* wsb = (char*)d_ws;
  size_t off = 0;
  int* hdr   = (int*)wsb;              off += 256;                // hdr[0] = num_unique
  int* keys  = (int*)(wsb + off);      off += (size_t)n * 4;
  int* slot  = (int*)(wsb + off);      off += (size_t)n * 4;
  off = (off + 255) & ~(size_t)255;
  int* cntk  = (int*)(wsb + off);      off += (size_t)NSC * 4;    // zeroed by k_zero
  int* rankK = (int*)(wsb + off);      off += (size_t)NSC * 4;
  int* posK  = (int*)(wsb + off);      off += (size_t)NSC * 4;
  int* mposK = (int*)(wsb + off);      off += (size_t)NSC * 4;
  unsigned long long* bsums = (unsigned long long*)(wsb + off); off += 512 * 8;
  unsigned long long* boffs = (unsigned long long*)(wsb + off); off += 512 * 8;
  unsigned short* Wbf = (unsigned short*)(wsb + off); off += (size_t)COUT * CIN * 2;
  off = (off + 255) & ~(size_t)255;
  char* tail = wsb + off;              off += (size_t)n * TAILB;
  off = (off + 255) & ~(size_t)255;
  unsigned short* ovf = (unsigned short*)(wsb + off);  off += (size_t)n * COUT * 2;

  int nb   = (int)((n + 255) / 256);
  int nb64 = (int)((n + 63) / 64);
  int ntail = (int)((n + 3) / 4);
  k_zero  <<<256, 256, 0, stream>>>((int4*)cntk, NSC / 4, (const float4*)W, Wbf);
  k_key   <<<nb, 256, 0, stream>>>(xyz, batch, keys, slot, cntk, (int)n);
  k_scan1 <<<NSC / 1024, 256, 0, stream>>>((const int4*)cntk, bsums);
  k_scan2 <<<1, 256, 0, stream>>>(bsums, boffs, hdr);
  k_scan3 <<<NSC / 1024, 256, 0, stream>>>((const int4*)cntk, boffs, rankK, posK, mposK);
  k_H     <<<nb64, 256, 0, stream>>>(feat, xyz, xyzc, batch, Wbf, gamma, beta,
                                     keys, slot, cntk, rankK, posK, mposK,
                                     out, ovf, tail, n);
  k_gat   <<<nb64 + ntail, 256, 0, stream>>>(tail, ovf, hdr, out, n, nb64);
}

// Round 10
// 236.467 us; speedup vs baseline: 3.7165x; 1.3038x over previous
//
#include <hip/hip_runtime.h>
#include <math.h>

constexpr int CIN   = 96;
constexpr int COUT  = 192;
constexpr int NSC   = 1 << 19;   // key space 8*40*40*40 = 512000 <= NSC
constexpr int LDW   = 104;       // Hl/Wl row stride (shorts)
constexpr int OST   = 208;       // Ol staging row stride (shorts, 416B)

typedef short v8s  __attribute__((ext_vector_type(8)));
typedef float f32x4 __attribute__((ext_vector_type(4)));

__device__ __forceinline__ unsigned short f2bf(float f) {
  unsigned u = __float_as_uint(f);
  u += 0x7fff + ((u >> 16) & 1);          // RNE
  return (unsigned short)(u >> 16);
}
__device__ __forceinline__ float bf2f(unsigned short s) {
  return __uint_as_float((unsigned)s << 16);
}
// fields: [62:42]=presence (rank), [41:21]=multi count (mpos), [20:0]=count (pos)
__device__ __forceinline__ unsigned long long pack3(int c) {
  return ((unsigned long long)(c > 0) << 42)
       | ((unsigned long long)((c >= 2) ? c : 0) << 21)
       | (unsigned long long)(unsigned)c;
}

// ---------------- zero cntk + bcnt + convert W -> bf16 ----------------
__global__ void k_zero(int4* __restrict__ cntk4, int n4, int* __restrict__ bcnt,
                       const float4* __restrict__ W4, unsigned short* __restrict__ Wbf) {
  int i = blockIdx.x * blockDim.x + threadIdx.x;
  int s = gridDim.x * blockDim.x;
  if (i == 0) *bcnt = 0;
  int4 z = make_int4(0, 0, 0, 0);
  for (int j = i; j < n4; j += s) cntk4[j] = z;
  for (int j = i; j < (COUT * CIN / 4); j += s) {
    float4 w = W4[j];
    uint2 pk;
    pk.x = (unsigned)f2bf(w.x) | ((unsigned)f2bf(w.y) << 16);
    pk.y = (unsigned)f2bf(w.z) | ((unsigned)f2bf(w.w) << 16);
    ((uint2*)Wbf)[j] = pk;
  }
}

// ---------------- keys + per-point slot + per-key counts ----------------
__global__ void k_key(const float* __restrict__ xyz, const int* __restrict__ batch,
                      int* __restrict__ keys, int* __restrict__ slot,
                      int* __restrict__ cntk, int n) {
  int i = blockIdx.x * blockDim.x + threadIdx.x;
  if (i >= n) return;
  int vx = min(max((int)floorf(xyz[3*i+0] * 0.5f), 0), 39);
  int vy = min(max((int)floorf(xyz[3*i+1] * 0.5f), 0), 39);
  int vz = min(max((int)floorf(xyz[3*i+2] * 0.5f), 0), 39);
  int key = ((batch[i] * 40 + vx) * 40 + vy) * 40 + vz;   // lexicographic, < 512000
  keys[i] = key;
  slot[i] = atomicAdd(&cntk[key], 1);
}

// ---------------- triple prefix scan ----------------
__global__ void k_scan1(const int4* __restrict__ cnt4,
                        unsigned long long* __restrict__ bsums) {
  int t = threadIdx.x;
  int4 v = cnt4[(size_t)blockIdx.x * 256 + t];
  unsigned long long s = pack3(v.x) + pack3(v.y) + pack3(v.z) + pack3(v.w);
  for (int o = 32; o; o >>= 1) s += __shfl_down(s, o);
  __shared__ unsigned long long wsum[4];
  if ((t & 63) == 0) wsum[t >> 6] = s;
  __syncthreads();
  if (t == 0) bsums[blockIdx.x] = wsum[0] + wsum[1] + wsum[2] + wsum[3];
}

__global__ void k_scan2(const unsigned long long* __restrict__ bsums,
                        unsigned long long* __restrict__ boffs,
                        int* __restrict__ hdr) {
  __shared__ unsigned long long tmp[256];
  int t = threadIdx.x;                      // 256 threads, 512 sums
  unsigned long long v0 = bsums[2*t], v1 = bsums[2*t+1];
  unsigned long long s = v0 + v1;
  tmp[t] = s;
  __syncthreads();
  for (int o = 1; o < 256; o <<= 1) {
    unsigned long long x = (t >= o) ? tmp[t - o] : 0ULL;
    __syncthreads();
    tmp[t] += x;
    __syncthreads();
  }
  unsigned long long base = tmp[t] - s;
  boffs[2*t] = base;
  boffs[2*t+1] = base + v0;
  if (t == 255) hdr[0] = (int)(tmp[255] >> 42);   // num_unique
}

__global__ void k_scan3(const int4* __restrict__ cnt4,
                        const unsigned long long* __restrict__ boffs,
                        int* __restrict__ rankK, int* __restrict__ posK,
                        int* __restrict__ mposK) {
  int t = threadIdx.x, b = blockIdx.x;
  int4 v = cnt4[(size_t)b * 256 + t];
  unsigned long long q0 = pack3(v.x), q1 = pack3(v.y), q2 = pack3(v.z), q3 = pack3(v.w);
  unsigned long long s = q0 + q1 + q2 + q3;
  __shared__ unsigned long long tmp[256];
  tmp[t] = s;
  __syncthreads();
  for (int o = 1; o < 256; o <<= 1) {
    unsigned long long x = (t >= o) ? tmp[t - o] : 0ULL;
    __syncthreads();
    tmp[t] += x;
    __syncthreads();
  }
  unsigned long long e0 = boffs[b] + tmp[t] - s;
  unsigned long long e1 = e0 + q0, e2 = e1 + q1, e3 = e2 + q2;
  const unsigned M = 0x1FFFFF;
  int4 rk = make_int4((int)(e0 >> 42), (int)(e1 >> 42), (int)(e2 >> 42), (int)(e3 >> 42));
  int4 mp = make_int4((int)((e0 >> 21) & M), (int)((e1 >> 21) & M),
                      (int)((e2 >> 21) & M), (int)((e3 >> 21) & M));
  int4 ps = make_int4((int)(e0 & M), (int)(e1 & M), (int)(e2 & M), (int)(e3 & M));
  ((int4*)rankK)[(size_t)b * 256 + t] = rk;
  ((int4*)posK )[(size_t)b * 256 + t] = ps;
  ((int4*)mposK)[(size_t)b * 256 + t] = mp;
}

// ---------------- permuted 32B record stream ----------------
// rec[p]: {xyz.x,y,z, c} | {pidx|batch<<20, base|cnt<<20, rank, mpos}
__global__ void k_plist(const float* __restrict__ xyz, const float* __restrict__ xyzc,
                        const int* __restrict__ batch, const int* __restrict__ keys,
                        const int* __restrict__ slot, const int* __restrict__ rankK,
                        const int* __restrict__ posK, const int* __restrict__ mposK,
                        const int* __restrict__ cntk, uint4* __restrict__ rec,
                        long long n) {
  long long i = (long long)blockIdx.x * blockDim.x + threadIdx.x;
  if (i >= n) return;
  int key = keys[i];
  int pos = posK[key], cnt = cntk[key], rank = rankK[key], mb = mposK[key];
  unsigned p = (unsigned)(pos + slot[i]);
  uint4 a, b;
  a.x = __float_as_uint(xyz[3*i+0]);
  a.y = __float_as_uint(xyz[3*i+1]);
  a.z = __float_as_uint(xyz[3*i+2]);
  a.w = __float_as_uint(xyzc[i]);
  b.x = (unsigned)i | ((unsigned)batch[i] << 20);
  b.y = (unsigned)pos | ((unsigned)cnt << 20);
  b.z = (unsigned)rank;
  b.w = (unsigned)mb;
  rec[(size_t)p*2+0] = a;
  rec[(size_t)p*2+1] = b;
}

// ---------------- LN + MFMA + in-window segment reduce (permuted order) ----------------
__global__ __launch_bounds__(256) void k_H(
    const float* __restrict__ feat, const unsigned short* __restrict__ Wbf,
    const float* __restrict__ gamma, const float* __restrict__ beta,
    const uint4* __restrict__ rec, float* __restrict__ out,
    unsigned short* __restrict__ ov, char* __restrict__ tail,
    uint4* __restrict__ blist, int* __restrict__ bcnt, long long n) {
  __shared__ unsigned short Wl[COUT * LDW];   // 39936B; reused as Ol[64][OST]
  __shared__ unsigned short Hl[64 * LDW];     // 13312B
  __shared__ float g_lds[CIN], b_lds[CIN];
  __shared__ int Tl[64][8];                   // staged records
  int t = threadIdx.x;
  if (t < CIN) { g_lds[t] = gamma[t]; b_lds[t] = beta[t]; }

  // ---- stage W (bf16): 2304 uint4, 9 per thread ----
  #pragma unroll
  for (int i = 0; i < 9; i++) {
    int j = t + 256 * i;
    uint4 w = ((const uint4*)Wbf)[j];
    int flat = j * 8;
    int row = flat / CIN, col = flat % CIN;
    *(uint4*)&Wl[row * LDW + col] = w;
  }

  // ---- stage 64 records (128 uint4) ----
  long long p0 = (long long)blockIdx.x * 64;
  if (t < 128) {
    long long sp = p0 + (t >> 1);
    if (sp < n) {
      uint4 v = rec[(size_t)sp * 2 + (t & 1)];
      *(uint4*)&Tl[t >> 1][(t & 1) * 4] = v;
    }
  }
  __syncthreads();                            // Wl, Tl, g/b ready

  // ---- LayerNorm: 4 threads per point (feat gathered via pidx) ----
  int p = t >> 2, q = t & 3;
  long long sp = p0 + p;
  float fv[24];
  float sum = 0.f, sq = 0.f;
  if (sp < n) {
    int pidx = Tl[p][4] & 0xFFFFF;
    const float* fr = feat + (size_t)pidx * CIN + q * 24;
    #pragma unroll
    for (int j = 0; j < 24; j += 4) {
      float4 x = *(const float4*)(fr + j);
      fv[j] = x.x; fv[j+1] = x.y; fv[j+2] = x.z; fv[j+3] = x.w;
    }
    #pragma unroll
    for (int j = 0; j < 24; j++) { sum += fv[j]; sq += fv[j] * fv[j]; }
  } else {
    #pragma unroll
    for (int j = 0; j < 24; j++) fv[j] = 0.f;
  }
  sum += __shfl_xor(sum, 1); sq += __shfl_xor(sq, 1);
  sum += __shfl_xor(sum, 2); sq += __shfl_xor(sq, 2);
  float mu   = sum * (1.f / CIN);
  float var  = sq  * (1.f / CIN) - mu * mu;
  float rstd = rsqrtf(var + 1e-6f);
  unsigned pk[12];
  #pragma unroll
  for (int j = 0; j < 12; j++) {
    int k = q * 24 + 2 * j;
    float v0 = (fv[2*j]   - mu) * rstd * g_lds[k]   + b_lds[k];
    float v1 = (fv[2*j+1] - mu) * rstd * g_lds[k+1] + b_lds[k+1];
    pk[j] = (unsigned)f2bf(v0) | ((unsigned)f2bf(v1) << 16);
  }
  {
    uint4* dst = (uint4*)&Hl[p * LDW + q * 24];
    dst[0] = make_uint4(pk[0], pk[1], pk[2],  pk[3]);
    dst[1] = make_uint4(pk[4], pk[5], pk[6],  pk[7]);
    dst[2] = make_uint4(pk[8], pk[9], pk[10], pk[11]);
  }
  __syncthreads();                            // Hl ready

  // ---- MFMA: 4 waves x 16 rows; N=192 (12 tiles), K=96 (3 steps) ----
  int wv = t >> 6, lane = t & 63, r = lane & 15, g = lane >> 4;
  f32x4 acc[12];
  #pragma unroll
  for (int i = 0; i < 12; i++) acc[i] = (f32x4){0.f, 0.f, 0.f, 0.f};
  int arow = (wv * 16 + r) * LDW;
  #pragma unroll
  for (int ks = 0; ks < 3; ks++) {
    v8s a = *(const v8s*)&Hl[arow + ks * 32 + g * 8];
    #pragma unroll
    for (int t16 = 0; t16 < 12; t16++) {
      v8s b = *(const v8s*)&Wl[(t16 * 16 + r) * LDW + ks * 32 + g * 8];
      acc[t16] = __builtin_amdgcn_mfma_f32_16x16x32_bf16(a, b, acc[t16], 0, 0, 0);
    }
  }
  __syncthreads();                            // Wl reads done -> reuse as Ol

  unsigned short* Ol = Wl;                    // [64][OST]
  #pragma unroll
  for (int t16 = 0; t16 < 12; t16++) {
    #pragma unroll
    for (int rr = 0; rr < 4; rr++) {
      Ol[(wv * 16 + g * 4 + rr) * OST + t16 * 16 + r] = f2bf(acc[t16][rr]);
    }
  }
  __syncthreads();                            // Ol complete

  // ---- epilogue: 4 threads per stream position ----
  int row = t >> 2, c4 = t & 3;
  long long sp2 = p0 + row;
  if (sp2 >= n) return;
  unsigned by = (unsigned)Tl[row][5];
  int base = (int)(by & 0xFFFFF), cnt = (int)(by >> 20);
  int rank = Tl[row][6], mb = Tl[row][7];
  bool interior = ((base >> 6) == ((base + cnt - 1) >> 6));
  float* ocrd = out + n * 192;
  float* oxyz = out + n * 196;
  float* ocnt = out + n * 199;
  float* obat = out + n * 200;
  float* oval = out + n * 201;
  if (interior) {
    if ((int)sp2 == base) {                   // head group reduces whole segment
      float* dst = out + (size_t)rank * COUT + c4 * 48;
      #pragma unroll
      for (int i = 0; i < 12; i++) {
        uint2 s2 = *(const uint2*)&Ol[row * OST + c4 * 48 + i * 4];
        float4 f;
        f.x = bf2f((unsigned short)(s2.x & 0xffff));
        f.y = bf2f((unsigned short)(s2.x >> 16));
        f.z = bf2f((unsigned short)(s2.y & 0xffff));
        f.w = bf2f((unsigned short)(s2.y >> 16));
        for (int k = 1; k < cnt; k++) {
          uint2 u = *(const uint2*)&Ol[(row + k) * OST + c4 * 48 + i * 4];
          f.x = fmaxf(f.x, bf2f((unsigned short)(u.x & 0xffff)));
          f.y = fmaxf(f.y, bf2f((unsigned short)(u.x >> 16)));
          f.z = fmaxf(f.z, bf2f((unsigned short)(u.y & 0xffff)));
          f.w = fmaxf(f.w, bf2f((unsigned short)(u.y >> 16)));
        }
        *(float4*)&dst[i * 4] = f;
      }
      if (c4 == 0) {                          // scalar finalize in-window
        float ax = 0.f, ay = 0.f, az = 0.f, ac = 0.f; int ab = 0;
        for (int k = 0; k < cnt; k++) {
          const int* T2 = Tl[row + k];
          float c = __int_as_float(T2[3]);
          ax += __int_as_float(T2[0]) * c;
          ay += __int_as_float(T2[1]) * c;
          az += __int_as_float(T2[2]) * c;
          ac += c;
          ab += (int)((unsigned)T2[4] >> 20);
        }
        float cs = fmaxf(ac, 1.0f);
        float x = ax / cs, y = ay / cs, z = az / cs;
        int bn = ab / max(cnt, 1);
        oxyz[(size_t)rank*3+0] = x; oxyz[(size_t)rank*3+1] = y; oxyz[(size_t)rank*3+2] = z;
        ocnt[rank] = cs;
        obat[rank] = (float)bn;
        oval[rank] = 1.0f;
        ocrd[(size_t)rank*4+0] = (float)bn;
        ocrd[(size_t)rank*4+1] = (float)(int)floorf(x * 0.5f);
        ocrd[(size_t)rank*4+2] = (float)(int)floorf(y * 0.5f);
        ocrd[(size_t)rank*4+3] = (float)(int)floorf(z * 0.5f);
      }
    }
  } else {                                    // boundary segment: spill row
    int sl = (int)sp2 - base;
    unsigned short* dst = ov + (size_t)(mb + sl) * COUT + c4 * 48;
    const unsigned short* src = &Ol[row * OST + c4 * 48];
    #pragma unroll
    for (int i = 0; i < 6; i++)
      ((uint4*)dst)[i] = ((const uint4*)src)[i];
    if (c4 == 0) {
      uint4* td = (uint4*)(tail + (size_t)sp2 * 32);
      td[0] = *(const uint4*)&Tl[row][0];
      td[1] = make_uint4((unsigned)Tl[row][4] >> 20, 0, 0, 0);
      if ((int)sp2 == base) {                 // head appends to boundary list
        int idx = atomicAdd(bcnt, 1);
        blist[idx] = make_uint4((unsigned)base, (unsigned)cnt,
                                (unsigned)rank, (unsigned)mb);
      }
    }
  }
}

// ---------------- boundary segments: wave per entry ----------------
__global__ __launch_bounds__(256) void k_bnd(
    const char* __restrict__ tail, const unsigned short* __restrict__ ov,
    const uint4* __restrict__ blist, const int* __restrict__ bcnt,
    float* __restrict__ out, long long n) {
  int lane = threadIdx.x & 63;
  int gw = blockIdx.x * 4 + (threadIdx.x >> 6);
  int nw = gridDim.x * 4;
  int m = *bcnt;
  float* ocrd = out + n * 192;
  float* oxyz = out + n * 196;
  float* ocnt = out + n * 199;
  float* obat = out + n * 200;
  float* oval = out + n * 201;
  for (int e = gw; e < m; e += nw) {
    uint4 be = blist[e];
    int base = (int)be.x, cnt = (int)be.y, rank = (int)be.z, mb = (int)be.w;
    float ni = __int_as_float(0xff800000);
    float m0 = ni, m1 = ni, m2 = ni;
    for (int qq = 0; qq < cnt; qq++) {
      const unsigned short* h = ov + (size_t)(mb + qq) * COUT;
      m0 = fmaxf(m0, bf2f(h[lane]));
      m1 = fmaxf(m1, bf2f(h[lane + 64]));
      m2 = fmaxf(m2, bf2f(h[lane + 128]));
    }
    float* orow = out + (size_t)rank * COUT;
    orow[lane] = m0; orow[lane + 64] = m1; orow[lane + 128] = m2;
    float ax = 0.f, ay = 0.f, az = 0.f, ac = 0.f; int ab = 0;
    for (int qq = lane; qq < cnt; qq += 64) {
      const float* tf = (const float*)(tail + (size_t)(base + qq) * 32);
      float c = tf[3];
      ax += tf[0] * c; ay += tf[1] * c; az += tf[2] * c; ac += c;
      ab += ((const int*)tf)[4];
    }
    for (int o = 32; o; o >>= 1) {
      ax += __shfl_down(ax, o); ay += __shfl_down(ay, o);
      az += __shfl_down(az, o); ac += __shfl_down(ac, o);
      ab += __shfl_down(ab, o);
    }
    if (lane == 0) {
      float cs = fmaxf(ac, 1.0f);
      float x = ax / cs, y = ay / cs, z = az / cs;
      int bn = ab / max(cnt, 1);
      oxyz[(size_t)rank*3+0] = x; oxyz[(size_t)rank*3+1] = y; oxyz[(size_t)rank*3+2] = z;
      ocnt[rank] = cs;
      obat[rank] = (float)bn;
      oval[rank] = 1.0f;
      ocrd[(size_t)rank*4+0] = (float)bn;
      ocrd[(size_t)rank*4+1] = (float)(int)floorf(x * 0.5f);
      ocrd[(size_t)rank*4+2] = (float)(int)floorf(y * 0.5f);
      ocrd[(size_t)rank*4+3] = (float)(int)floorf(z * 0.5f);
    }
  }
}

// ---------------- tail rows >= num_unique ----------------
__global__ void k_tail(float* __restrict__ out, const int* __restrict__ hdr, long long n) {
  int nu = hdr[0];
  long long s = (long long)blockIdx.x * 4 + (threadIdx.x >> 6);
  if (s < nu || s >= n) return;
  int lane = threadIdx.x & 63;
  float* orow = out + s * COUT;
  orow[lane] = 0.f; orow[lane + 64] = 0.f; orow[lane + 128] = 0.f;
  if (lane == 0) {
    float* ocrd = out + n * 192;
    float* oxyz = out + n * 196;
    float* ocnt = out + n * 199;
    float* obat = out + n * 200;
    float* oval = out + n * 201;
    oxyz[s*3+0] = 0.f; oxyz[s*3+1] = 0.f; oxyz[s*3+2] = 0.f;
    ocnt[s] = 1.0f;
    obat[s] = 0.f;
    oval[s] = 0.f;
    ocrd[s*4+0] = 0.f; ocrd[s*4+1] = 0.f; ocrd[s*4+2] = 0.f; ocrd[s*4+3] = 0.f;
  }
}

extern "C" void kernel_launch(void* const* d_in, const int* in_sizes, int n_in,
                              void* d_out, int out_size, void* d_ws, size_t ws_size,
                              hipStream_t stream) {
  const float* feat  = (const float*)d_in[0];
  const float* xyz   = (const float*)d_in[1];
  const float* xyzc  = (const float*)d_in[2];
  const int*   batch = (const int*)d_in[3];
  const float* W     = (const float*)d_in[4];
  const float* gamma = (const float*)d_in[5];
  const float* beta  = (const float*)d_in[6];
  long long n = in_sizes[3];
  float* out = (float*)d_out;

  // ---- workspace layout (~210 MB) ----
  char* wsb = (char*)d_ws;
  size_t off = 0;
  int* hdr   = (int*)wsb;              off += 256;         // hdr[0]=nu, hdr[1]=bcnt
  int* keys  = (int*)(wsb + off);      off += (size_t)n * 4;
  int* slot  = (int*)(wsb + off);      off += (size_t)n * 4;
  off = (off + 255) & ~(size_t)255;
  int* cntk  = (int*)(wsb + off);      off += (size_t)NSC * 4;    // zeroed by k_zero
  int* rankK = (int*)(wsb + off);      off += (size_t)NSC * 4;
  int* posK  = (int*)(wsb + off);      off += (size_t)NSC * 4;
  int* mposK = (int*)(wsb + off);      off += (size_t)NSC * 4;
  unsigned long long* bsums = (unsigned long long*)(wsb + off); off += 512 * 8;
  unsigned long long* boffs = (unsigned long long*)(wsb + off); off += 512 * 8;
  unsigned short* Wbf = (unsigned short*)(wsb + off); off += (size_t)COUT * CIN * 2;
  off = (off + 255) & ~(size_t)255;
  uint4* blist = (uint4*)(wsb + off);  off += (size_t)65536 * 16;
  char* tailr  = wsb + off;            off += (size_t)n * 32;
  uint4* rec   = (uint4*)(wsb + off);  off += (size_t)n * 32;
  off = (off + 255) & ~(size_t)255;
  unsigned short* ovf = (unsigned short*)(wsb + off);  off += (size_t)n * COUT * 2;

  int nb   = (int)((n + 255) / 256);
  int nb64 = (int)((n + 63) / 64);
  int ntail = (int)((n + 3) / 4);
  k_zero  <<<256, 256, 0, stream>>>((int4*)cntk, NSC / 4, &hdr[1], (const float4*)W, Wbf);
  k_key   <<<nb, 256, 0, stream>>>(xyz, batch, keys, slot, cntk, (int)n);
  k_scan1 <<<NSC / 1024, 256, 0, stream>>>((const int4*)cntk, bsums);
  k_scan2 <<<1, 256, 0, stream>>>(bsums, boffs, hdr);
  k_scan3 <<<NSC / 1024, 256, 0, stream>>>((const int4*)cntk, boffs, rankK, posK, mposK);
  k_plist <<<nb, 256, 0, stream>>>(xyz, xyzc, batch, keys, slot, rankK, posK, mposK,
                                   cntk, rec, n);
  k_H     <<<nb64, 256, 0, stream>>>(feat, Wbf, gamma, beta, rec, out, ovf, tailr,
                                     blist, &hdr[1], n);
  k_bnd   <<<256, 256, 0, stream>>>(tailr, ovf, blist, &hdr[1], out, n);
  k_tail  <<<ntail, 256, 0, stream>>>(out, hdr, n);
}